// Round 8
// baseline (59.574 us; speedup 1.0000x reference)
//
#include <hip/hip_runtime.h>
#include <stdint.h>

using bf16x8_t = __attribute__((ext_vector_type(8))) __bf16;
using f32x4_t  = __attribute__((ext_vector_type(4))) float;
using u16x8_t  = __attribute__((ext_vector_type(8))) unsigned short;

#define KD 2048

static __device__ __forceinline__ unsigned short f2bf(float f) {
  union { float f; unsigned u; } v; v.f = f;
  unsigned r = v.u + 0x7fffu + ((v.u >> 16) & 1u);   // RNE
  return (unsigned short)(r >> 16);
}

// ---- single fused prep, grid 400 ----
// blocks 0..127:   pack 9-frag bf16 W: dst ((s*9+nf)*64+l)*8+j <->
//                  B[col=nf*16+(l&15)][k=s*32+(l>>4)*8+j]; cols 0..63=w_a, 64..127=w_b.
// blocks 128..383: ws[h]=sum_d wqkv[d][h]+wz[d][h] (8 cols/block, fixed tree),
//                  written as bf16 directly into frag-8 slots (col 128).
// blocks 384..399: zero frag-8 slots for lanes (l&15)!=0 (cols 129..143).
__global__ void k_prep(const float* __restrict__ wqkv, const float* __restrict__ wz,
                       const float* __restrict__ wb, const float* __restrict__ wa,
                       unsigned short* __restrict__ wbf3) {
  __shared__ float red[4][8];
  const int b = blockIdx.x, t = threadIdx.x;
  if (b < 128) {
    const int u = b * 256 + t;                   // (s,nf,l) over nf<8
    const int l = u & 63;
    const int vv = u >> 6;
    const int nf = vv & 7;
    const int s  = vv >> 3;
    const int k  = s * 32 + ((l >> 4) << 3);
    const int c  = nf * 16 + (l & 15);
    const float* src = (c < 64) ? (wa + (size_t)c * KD + k)
                                : (wb + (size_t)(c - 64) * KD + k);
    f32x4_t v0 = *(const f32x4_t*)(src);
    f32x4_t v1 = *(const f32x4_t*)(src + 4);
    u16x8_t o;
    o[0]=f2bf(v0[0]); o[1]=f2bf(v0[1]); o[2]=f2bf(v0[2]); o[3]=f2bf(v0[3]);
    o[4]=f2bf(v1[0]); o[5]=f2bf(v1[1]); o[6]=f2bf(v1[2]); o[7]=f2bf(v1[3]);
    *(u16x8_t*)(wbf3 + (size_t)((s * 9 + nf) * 64 + l) * 8) = o;
  } else if (b < 384) {
    const int bw = b - 128;                      // cols h = bw*8 .. bw*8+7
    const int c = t & 7;
    const int rg = t >> 3;                       // 0..31
    const int h = bw * 8 + c;
    float s = 0.f;
    #pragma unroll 8
    for (int i = 0; i < 40; ++i) {
      const int r = rg + 32 * i;                 // 0..1279
      const float* p = (r < 768) ? (wqkv + (size_t)r * KD)
                                 : (wz + (size_t)(r - 768) * KD);
      s += p[h];
    }
    s += __shfl_xor(s, 8, 64);
    s += __shfl_xor(s, 16, 64);
    s += __shfl_xor(s, 32, 64);
    const int lane = t & 63, wv = t >> 6;
    if (lane < 8) red[wv][lane] = s;
    __syncthreads();
    if (t < 8) {
      const float val = red[0][t] + red[1][t] + red[2][t] + red[3][t];
      const int hh = bw * 8 + t;                 // k index 0..2047
      const int s9 = hh >> 5;                    // K-step
      const int g  = (hh & 31) >> 3;             // k-group
      const int j  = hh & 7;
      wbf3[(size_t)((s9 * 9 + 8) * 64 + (g << 4)) * 8 + j] = f2bf(val);
    }
  } else {
    const int idx = (b - 384) * 256 + t;         // (s,l) 0..4095
    const int s = idx >> 6, l = idx & 63;
    if (l & 15) {
      u16x8_t z; z[0]=0;z[1]=0;z[2]=0;z[3]=0;z[4]=0;z[5]=0;z[6]=0;z[7]=0;
      *(u16x8_t*)(wbf3 + (size_t)((s * 9 + 8) * 64 + l) * 8) = z;
    }
  }
}

// ---- main: BM=64 (4 waves x 16 rows), BK=32, 64 K-steps, 9 W-frags.
// Counted-vmcnt pipeline: X 3-buf (staged 2 ahead), W 2-buf (1 ahead);
// steady wait = vmcnt(2) (leaves X(it+1) in flight; drains X(it),W(it)).
// wsum rides as B-frag 8 (col 128, cols 129-143 zero) -> s0 = acc[8][r],
// no ws LDS / VALU dot / epilogue shuffle. LDS: 3x8K X + 2x9K W = 42 KB
// -> 3 blocks/CU. X chunks wave-private; W chunk 8 staged by wave 0.
__global__ __launch_bounds__(256, 3) void k_main(
    const float* __restrict__ x, const unsigned short* __restrict__ wbf3,
    float* __restrict__ out)
{
  __shared__ __align__(16) unsigned char lds[43008];   // 24576 X | 18432 W
  const int t = threadIdx.x;
  const int lane = t & 63;
  const int wv = t >> 6;
  const int g = lane >> 4;        // k-group 0..3
  const int r15 = lane & 15;
  const size_t tile = (size_t)blockIdx.x * 64;

  f32x4_t acc[9];
  #pragma unroll
  for (int i = 0; i < 9; ++i) acc[i] = f32x4_t{0.f, 0.f, 0.f, 0.f};

  // W stage: 9 chunks of 1KB; wave wv takes {wv*2, wv*2+1}, wave 0 also chunk 8
  auto STAGE_W = [&](int it) {
    unsigned char* wbp = lds + 24576 + (it & 1) * 9216;
    const unsigned short* gw = wbf3 + (size_t)it * 4608 + lane * 8;
    #pragma unroll
    for (int i = 0; i < 2; ++i) {
      const int ch = wv * 2 + i;
      __builtin_amdgcn_global_load_lds(
          (const __attribute__((address_space(1))) void*)(gw + ch * 512),
          (__attribute__((address_space(3))) void*)(wbp + ch * 1024), 16, 0, 0);
    }
    if (wv == 0)
      __builtin_amdgcn_global_load_lds(
          (const __attribute__((address_space(1))) void*)(gw + 8 * 512),
          (__attribute__((address_space(3))) void*)(wbp + 8 * 1024), 16, 0, 0);
  };
  // X stage: 8 chunks of 1KB (8 rows x 128B); wave-private rows.
  // LDS[row][slot] holds global slot (slot ^ (row&7))  (XOR swizzle).
  auto STAGE_X = [&](int it, int bsel) {
    unsigned char* xbp = lds + bsel * 8192;
    #pragma unroll
    for (int i = 0; i < 2; ++i) {
      const int ch = wv * 2 + i;
      const int r = ch * 8 + (lane >> 3);          // row within tile
      const int c = (lane & 7) ^ (r & 7);          // source 16B slot
      const float* src = x + (tile + r) * KD + it * 32 + c * 4;
      __builtin_amdgcn_global_load_lds(
          (const __attribute__((address_space(1))) void*)src,
          (__attribute__((address_space(3))) void*)(xbp + ch * 1024), 16, 0, 0);
    }
  };
  auto COMPUTE = [&](int it, int xbsel) {
    const unsigned char* xbp = lds + xbsel * 8192;
    const unsigned char* wbp = lds + 24576 + (it & 1) * 9216;
    const int r = wv * 16 + r15;
    const unsigned char* xr = xbp + r * 128;
    f32x4_t lo = *(const f32x4_t*)(xr + (((g * 2)     ^ (r15 & 7)) * 16));
    f32x4_t hi = *(const f32x4_t*)(xr + (((g * 2 + 1) ^ (r15 & 7)) * 16));
    bf16x8_t af;
    af[0] = (__bf16)lo[0]; af[1] = (__bf16)lo[1];
    af[2] = (__bf16)lo[2]; af[3] = (__bf16)lo[3];
    af[4] = (__bf16)hi[0]; af[5] = (__bf16)hi[1];
    af[6] = (__bf16)hi[2]; af[7] = (__bf16)hi[3];
    #pragma unroll
    for (int nf = 0; nf < 9; ++nf) {
      bf16x8_t bfr = *(const bf16x8_t*)(wbp + (nf * 64 + lane) * 16);
      acc[nf] = __builtin_amdgcn_mfma_f32_16x16x32_bf16(af, bfr, acc[nf], 0, 0, 0);
    }
  };

  // prologue: W(0), X(0), X(1)
  STAGE_W(0);
  STAGE_X(0, 0);
  STAGE_X(1, 1);

  int xb = 0;                                      // buffer of tile `it` (it % 3)
  for (int it = 0; it < 63; ++it) {
    // drains X(it), W(it); leaves X(it+1) (2 loads) in flight
    asm volatile("s_waitcnt vmcnt(2)" ::: "memory");
    __builtin_amdgcn_s_barrier();
    __builtin_amdgcn_sched_barrier(0);
    STAGE_W(it + 1);                               // buf (it+1)&1, freed by barrier
    if (it < 62) {
      int b2 = xb + 2; if (b2 >= 3) b2 -= 3;
      STAGE_X(it + 2, b2);                         // buf (it+2)%3, freed by barrier
    }
    COMPUTE(it, xb);
    ++xb; if (xb == 3) xb = 0;
  }
  // peeled last step: full drain
  asm volatile("s_waitcnt vmcnt(0)" ::: "memory");
  __builtin_amdgcn_s_barrier();
  __builtin_amdgcn_sched_barrier(0);
  COMPUTE(63, xb);

  // epilogue: C col=lane&15, row=g*4+reg; a-frag nf pairs with b-frag nf+4.
  // acc[8][r] (col 128) = qkv+z fold, already at the writer lane (r15==0).
  #pragma unroll
  for (int r = 0; r < 4; ++r) {
    float v = 0.f;
    #pragma unroll
    for (int nf = 0; nf < 4; ++nf) {
      float av = acc[nf][r];
      float bv = acc[nf + 4][r];
      v += av / (1.f + __expf(-bv));          // a * sigmoid(b)
    }
    v += __shfl_xor(v, 1, 64);
    v += __shfl_xor(v, 2, 64);
    v += __shfl_xor(v, 4, 64);
    v += __shfl_xor(v, 8, 64);
    if (r15 == 0) out[tile + wv * 16 + g * 4 + r] = v + acc[8][r];
  }
}

extern "C" void kernel_launch(void* const* d_in, const int* in_sizes, int n_in,
                              void* d_out, int out_size, void* d_ws, size_t ws_size,
                              hipStream_t stream) {
  const float* x    = (const float*)d_in[0];
  const float* wqkv = (const float*)d_in[1];
  const float* wz   = (const float*)d_in[2];
  const float* wb   = (const float*)d_in[3];   // dict order: w_b before w_a
  const float* wa   = (const float*)d_in[4];
  float* out = (float*)d_out;

  unsigned short* wbf3 = (unsigned short*)d_ws;  // 64*9*64*8 shorts = 576 KB

  k_prep<<<400, 256, 0, stream>>>(wqkv, wz, wb, wa, wbf3);
  k_main<<<out_size / 64, 256, 0, stream>>>(x, wbf3, out);
}

// Round 9
// 55.719 us; speedup vs baseline: 1.0692x; 1.0692x over previous
//
#include <hip/hip_runtime.h>
#include <stdint.h>

using bf16x8_t = __attribute__((ext_vector_type(8))) __bf16;
using f32x4_t  = __attribute__((ext_vector_type(4))) float;
using u16x8_t  = __attribute__((ext_vector_type(8))) unsigned short;

#define KD 2048

static __device__ __forceinline__ unsigned short f2bf(float f) {
  union { float f; unsigned u; } v; v.f = f;
  unsigned r = v.u + 0x7fffu + ((v.u >> 16) & 1u);   // RNE
  return (unsigned short)(r >> 16);
}

// ---- single fused prep, grid 400 ----
// blocks 0..127:   pack 9-frag bf16 W: dst ((s*9+nf)*64+l)*8+j <->
//                  B[col=nf*16+(l&15)][k=s*32+(l>>4)*8+j]; cols 0..63=w_a, 64..127=w_b.
// blocks 128..383: ws[h]=sum_d wqkv[d][h]+wz[d][h] (8 cols/block, fixed tree),
//                  written as bf16 into frag-8 slots (col 128).
// blocks 384..399: zero frag-8 slots for lanes (l&15)!=0 (cols 129..143).
__global__ void k_prep(const float* __restrict__ wqkv, const float* __restrict__ wz,
                       const float* __restrict__ wb, const float* __restrict__ wa,
                       unsigned short* __restrict__ wbf3) {
  __shared__ float red[4][8];
  const int b = blockIdx.x, t = threadIdx.x;
  if (b < 128) {
    const int u = b * 256 + t;                   // (s,nf,l) over nf<8
    const int l = u & 63;
    const int vv = u >> 6;
    const int nf = vv & 7;
    const int s  = vv >> 3;
    const int k  = s * 32 + ((l >> 4) << 3);
    const int c  = nf * 16 + (l & 15);
    const float* src = (c < 64) ? (wa + (size_t)c * KD + k)
                                : (wb + (size_t)(c - 64) * KD + k);
    f32x4_t v0 = *(const f32x4_t*)(src);
    f32x4_t v1 = *(const f32x4_t*)(src + 4);
    u16x8_t o;
    o[0]=f2bf(v0[0]); o[1]=f2bf(v0[1]); o[2]=f2bf(v0[2]); o[3]=f2bf(v0[3]);
    o[4]=f2bf(v1[0]); o[5]=f2bf(v1[1]); o[6]=f2bf(v1[2]); o[7]=f2bf(v1[3]);
    *(u16x8_t*)(wbf3 + (size_t)((s * 9 + nf) * 64 + l) * 8) = o;
  } else if (b < 384) {
    const int bw = b - 128;                      // cols h = bw*8 .. bw*8+7
    const int c = t & 7;
    const int rg = t >> 3;                       // 0..31
    const int h = bw * 8 + c;
    float s = 0.f;
    #pragma unroll 8
    for (int i = 0; i < 40; ++i) {
      const int r = rg + 32 * i;                 // 0..1279
      const float* p = (r < 768) ? (wqkv + (size_t)r * KD)
                                 : (wz + (size_t)(r - 768) * KD);
      s += p[h];
    }
    s += __shfl_xor(s, 8, 64);
    s += __shfl_xor(s, 16, 64);
    s += __shfl_xor(s, 32, 64);
    const int lane = t & 63, wv = t >> 6;
    if (lane < 8) red[wv][lane] = s;
    __syncthreads();
    if (t < 8) {
      const float val = red[0][t] + red[1][t] + red[2][t] + red[3][t];
      const int hh = bw * 8 + t;                 // k index 0..2047
      const int s9 = hh >> 5;                    // K-step
      const int g  = (hh & 31) >> 3;             // k-group
      const int j  = hh & 7;
      wbf3[(size_t)((s9 * 9 + 8) * 64 + (g << 4)) * 8 + j] = f2bf(val);
    }
  } else {
    const int idx = (b - 384) * 256 + t;         // (s,l) 0..4095
    const int s = idx >> 6, l = idx & 63;
    if (l & 15) {
      u16x8_t z; z[0]=0;z[1]=0;z[2]=0;z[3]=0;z[4]=0;z[5]=0;z[6]=0;z[7]=0;
      *(u16x8_t*)(wbf3 + (size_t)((s * 9 + 8) * 64 + l) * 8) = z;
    }
  }
}

// ---- main: BM=128, 8 waves x 16 rows, BK=32, 64 K-steps, 9 W-frags.
// Grid 256 (1 block/CU) -> W is streamed from L2 only 256x (vs 2048x at BM=64):
// W L2 traffic 1.18 GB -> 151 MB, removing L2 contention from the vmcnt path.
// Counted-vmcnt pipeline: X 3-buf (2 ahead), W 2-buf (1 ahead); per-wave queue
// entering it = [W(it), X(it), X(it+1)] -> steady wait vmcnt(2) leaves X(it+1)
// in flight. LDS: 3x16K X + 2x9.2K W = 66.4 KB. X chunks wave-private.
__global__ __launch_bounds__(512, 1) void k_main(
    const float* __restrict__ x, const unsigned short* __restrict__ wbf3,
    float* __restrict__ out)
{
  __shared__ __align__(16) unsigned char lds[67584];   // 49152 X | 18432 W
  const int t = threadIdx.x;
  const int lane = t & 63;
  const int wv = t >> 6;          // 0..7
  const int g = lane >> 4;        // k-group 0..3
  const int r15 = lane & 15;
  const size_t tile = (size_t)blockIdx.x * 128;

  f32x4_t acc[9];
  #pragma unroll
  for (int i = 0; i < 9; ++i) acc[i] = f32x4_t{0.f, 0.f, 0.f, 0.f};

  // W stage: 9 chunks of 1KB; wave wv takes chunk wv, wave 0 also chunk 8
  auto STAGE_W = [&](int it) {
    unsigned char* wbp = lds + 49152 + (it & 1) * 9216;
    const unsigned short* gw = wbf3 + (size_t)it * 4608 + lane * 8;
    __builtin_amdgcn_global_load_lds(
        (const __attribute__((address_space(1))) void*)(gw + wv * 512),
        (__attribute__((address_space(3))) void*)(wbp + wv * 1024), 16, 0, 0);
    if (wv == 0)
      __builtin_amdgcn_global_load_lds(
          (const __attribute__((address_space(1))) void*)(gw + 8 * 512),
          (__attribute__((address_space(3))) void*)(wbp + 8 * 1024), 16, 0, 0);
  };
  // X stage: 16 chunks of 1KB (8 rows x 128B each); wave wv takes {wv*2, wv*2+1}.
  // LDS[row][slot] holds global slot (slot ^ (row&7))  (XOR swizzle).
  auto STAGE_X = [&](int it, int bsel) {
    unsigned char* xbp = lds + bsel * 16384;
    #pragma unroll
    for (int i = 0; i < 2; ++i) {
      const int ch = wv * 2 + i;                   // 0..15
      const int r = ch * 8 + (lane >> 3);          // row within tile 0..127
      const int c = (lane & 7) ^ (r & 7);          // source 16B slot
      const float* src = x + (tile + r) * KD + it * 32 + c * 4;
      __builtin_amdgcn_global_load_lds(
          (const __attribute__((address_space(1))) void*)src,
          (__attribute__((address_space(3))) void*)(xbp + ch * 1024), 16, 0, 0);
    }
  };
  auto COMPUTE = [&](int it, int xbsel) {
    const unsigned char* xbp = lds + xbsel * 16384;
    const unsigned char* wbp = lds + 49152 + (it & 1) * 9216;
    const int r = wv * 16 + r15;                   // 0..127
    const unsigned char* xr = xbp + r * 128;
    f32x4_t lo = *(const f32x4_t*)(xr + (((g * 2)     ^ (r15 & 7)) * 16));
    f32x4_t hi = *(const f32x4_t*)(xr + (((g * 2 + 1) ^ (r15 & 7)) * 16));
    bf16x8_t af;
    af[0] = (__bf16)lo[0]; af[1] = (__bf16)lo[1];
    af[2] = (__bf16)lo[2]; af[3] = (__bf16)lo[3];
    af[4] = (__bf16)hi[0]; af[5] = (__bf16)hi[1];
    af[6] = (__bf16)hi[2]; af[7] = (__bf16)hi[3];
    #pragma unroll
    for (int nf = 0; nf < 9; ++nf) {
      bf16x8_t bfr = *(const bf16x8_t*)(wbp + (nf * 64 + lane) * 16);
      acc[nf] = __builtin_amdgcn_mfma_f32_16x16x32_bf16(af, bfr, acc[nf], 0, 0, 0);
    }
  };

  // prologue: W(0), X(0), X(1)  -> per-wave queue: [W(0), X(0), X(1)]
  STAGE_W(0);
  STAGE_X(0, 0);
  STAGE_X(1, 1);

  int xb = 0;                                      // buffer of tile `it` (it % 3)
  for (int it = 0; it < 63; ++it) {
    // drains W(it), X(it); leaves X(it+1) (2 loads/wave) in flight
    asm volatile("s_waitcnt vmcnt(2)" ::: "memory");
    __builtin_amdgcn_s_barrier();
    __builtin_amdgcn_sched_barrier(0);
    STAGE_W(it + 1);                               // buf (it+1)&1, freed by barrier
    if (it < 62) {
      int b2 = xb + 2; if (b2 >= 3) b2 -= 3;
      STAGE_X(it + 2, b2);                         // buf (it+2)%3, freed by barrier
    }
    COMPUTE(it, xb);
    ++xb; if (xb == 3) xb = 0;
  }
  // peeled last step: full drain
  asm volatile("s_waitcnt vmcnt(0)" ::: "memory");
  __builtin_amdgcn_s_barrier();
  __builtin_amdgcn_sched_barrier(0);
  COMPUTE(63, xb);

  // epilogue: C col=lane&15, row=g*4+reg; a-frag nf pairs with b-frag nf+4.
  // acc[8][r] (col 128) = qkv+z fold, already at the writer lane (r15==0).
  #pragma unroll
  for (int r = 0; r < 4; ++r) {
    float v = 0.f;
    #pragma unroll
    for (int nf = 0; nf < 4; ++nf) {
      float av = acc[nf][r];
      float bv = acc[nf + 4][r];
      v += av / (1.f + __expf(-bv));          // a * sigmoid(b)
    }
    v += __shfl_xor(v, 1, 64);
    v += __shfl_xor(v, 2, 64);
    v += __shfl_xor(v, 4, 64);
    v += __shfl_xor(v, 8, 64);
    if (r15 == 0) out[tile + wv * 16 + g * 4 + r] = v + acc[8][r];
  }
}

extern "C" void kernel_launch(void* const* d_in, const int* in_sizes, int n_in,
                              void* d_out, int out_size, void* d_ws, size_t ws_size,
                              hipStream_t stream) {
  const float* x    = (const float*)d_in[0];
  const float* wqkv = (const float*)d_in[1];
  const float* wz   = (const float*)d_in[2];
  const float* wb   = (const float*)d_in[3];   // dict order: w_b before w_a
  const float* wa   = (const float*)d_in[4];
  float* out = (float*)d_out;

  unsigned short* wbf3 = (unsigned short*)d_ws;  // 64*9*64*8 shorts = 576 KB

  k_prep<<<400, 256, 0, stream>>>(wqkv, wz, wb, wa, wbf3);
  k_main<<<out_size / 128, 512, 0, stream>>>(x, wbf3, out);
}

// Round 10
// 54.994 us; speedup vs baseline: 1.0833x; 1.0132x over previous
//
#include <hip/hip_runtime.h>
#include <stdint.h>

using bf16x8_t = __attribute__((ext_vector_type(8))) __bf16;
using f32x4_t  = __attribute__((ext_vector_type(4))) float;
using u16x8_t  = __attribute__((ext_vector_type(8))) unsigned short;

#define KD 2048

static __device__ __forceinline__ unsigned short f2bf(float f) {
  union { float f; unsigned u; } v; v.f = f;
  unsigned r = v.u + 0x7fffu + ((v.u >> 16) & 1u);   // RNE
  return (unsigned short)(r >> 16);
}

// ---- single fused prep, grid 400 (layout identical to R8/R9) ----
// blocks 0..127:   pack 9-frag bf16 W: dst ((s*9+nf)*64+l)*8+j <->
//                  B[col=nf*16+(l&15)][k=s*32+(l>>4)*8+j]; cols 0..63=w_a, 64..127=w_b.
// blocks 128..383: ws[h]=sum_d wqkv[d][h]+wz[d][h] -> bf16 into frag-8 (col 128).
// blocks 384..399: zero frag-8 slots for lanes (l&15)!=0 (cols 129..143).
__global__ void k_prep(const float* __restrict__ wqkv, const float* __restrict__ wz,
                       const float* __restrict__ wb, const float* __restrict__ wa,
                       unsigned short* __restrict__ wbf3) {
  __shared__ float red[4][8];
  const int b = blockIdx.x, t = threadIdx.x;
  if (b < 128) {
    const int u = b * 256 + t;                   // (s,nf,l) over nf<8
    const int l = u & 63;
    const int vv = u >> 6;
    const int nf = vv & 7;
    const int s  = vv >> 3;
    const int k  = s * 32 + ((l >> 4) << 3);
    const int c  = nf * 16 + (l & 15);
    const float* src = (c < 64) ? (wa + (size_t)c * KD + k)
                                : (wb + (size_t)(c - 64) * KD + k);
    f32x4_t v0 = *(const f32x4_t*)(src);
    f32x4_t v1 = *(const f32x4_t*)(src + 4);
    u16x8_t o;
    o[0]=f2bf(v0[0]); o[1]=f2bf(v0[1]); o[2]=f2bf(v0[2]); o[3]=f2bf(v0[3]);
    o[4]=f2bf(v1[0]); o[5]=f2bf(v1[1]); o[6]=f2bf(v1[2]); o[7]=f2bf(v1[3]);
    *(u16x8_t*)(wbf3 + (size_t)((s * 9 + nf) * 64 + l) * 8) = o;
  } else if (b < 384) {
    const int bw = b - 128;                      // cols h = bw*8 .. bw*8+7
    const int c = t & 7;
    const int rg = t >> 3;                       // 0..31
    const int h = bw * 8 + c;
    float s = 0.f;
    #pragma unroll 8
    for (int i = 0; i < 40; ++i) {
      const int r = rg + 32 * i;                 // 0..1279
      const float* p = (r < 768) ? (wqkv + (size_t)r * KD)
                                 : (wz + (size_t)(r - 768) * KD);
      s += p[h];
    }
    s += __shfl_xor(s, 8, 64);
    s += __shfl_xor(s, 16, 64);
    s += __shfl_xor(s, 32, 64);
    const int lane = t & 63, wv = t >> 6;
    if (lane < 8) red[wv][lane] = s;
    __syncthreads();
    if (t < 8) {
      const float val = red[0][t] + red[1][t] + red[2][t] + red[3][t];
      const int hh = bw * 8 + t;                 // k index 0..2047
      const int s9 = hh >> 5;                    // K-step (32-granular)
      const int g  = (hh & 31) >> 3;             // k-group
      const int j  = hh & 7;
      wbf3[(size_t)((s9 * 9 + 8) * 64 + (g << 4)) * 8 + j] = f2bf(val);
    }
  } else {
    const int idx = (b - 384) * 256 + t;         // (s,l) 0..4095
    const int s = idx >> 6, l = idx & 63;
    if (l & 15) {
      u16x8_t z; z[0]=0;z[1]=0;z[2]=0;z[3]=0;z[4]=0;z[5]=0;z[6]=0;z[7]=0;
      *(u16x8_t*)(wbf3 + (size_t)((s * 9 + 8) * 64 + l) * 8) = z;
    }
  }
}

// ---- main: BM=128 (8 waves x 16 rows), BK=64, 32 K-steps, 9 W-frags x 2 k-halves.
// Counted-vmcnt pipeline: X 3-buf of 32 KB (staged 2 ahead), W 2-buf of 18 KB
// (1 ahead). Steady per-wave queue entering iter = [W(it):2-3, X(it):4,
// X(it+1):4] -> vmcnt(4) drains W(it)+X(it), leaves X(it+1) (32 KB/CU) in
// flight across the barrier. 32 barriers (half of R9); 256 B/row DRAM segments.
// LDS: 3x32K X + 2x18K W = 132 KB -> 1 block/CU (grid 256).
__global__ __launch_bounds__(512, 1) void k_main(
    const float* __restrict__ x, const unsigned short* __restrict__ wbf3,
    float* __restrict__ out)
{
  __shared__ __align__(16) unsigned char lds[135168];  // 98304 X | 36864 W
  const int t = threadIdx.x;
  const int lane = t & 63;
  const int wv = t >> 6;          // 0..7
  const int g = lane >> 4;        // k-group 0..3
  const int r15 = lane & 15;
  const size_t tile = (size_t)blockIdx.x * 128;

  f32x4_t acc[9];
  #pragma unroll
  for (int i = 0; i < 9; ++i) acc[i] = f32x4_t{0.f, 0.f, 0.f, 0.f};

  // W stage: 18 chunks of 1KB (2 k-half steps x 9 frags, linear in wbf3);
  // wave wv takes {wv, wv+8}; waves 0,1 also take {16,17}.
  auto STAGE_W = [&](int it) {
    unsigned char* wbp = lds + 98304 + (it & 1) * 18432;
    const unsigned short* gw = wbf3 + (size_t)it * 9216 + lane * 8;
    __builtin_amdgcn_global_load_lds(
        (const __attribute__((address_space(1))) void*)(gw + wv * 512),
        (__attribute__((address_space(3))) void*)(wbp + wv * 1024), 16, 0, 0);
    __builtin_amdgcn_global_load_lds(
        (const __attribute__((address_space(1))) void*)(gw + (wv + 8) * 512),
        (__attribute__((address_space(3))) void*)(wbp + (wv + 8) * 1024), 16, 0, 0);
    if (wv < 2)
      __builtin_amdgcn_global_load_lds(
          (const __attribute__((address_space(1))) void*)(gw + (16 + wv) * 512),
          (__attribute__((address_space(3))) void*)(wbp + (16 + wv) * 1024), 16, 0, 0);
  };
  // X stage: 32 chunks of 1KB; chunk ch = rows ch*4..ch*4+3 (256 B/row).
  // Wave wv takes chunks wv*4..wv*4+3 (its own 16 rows). Within a chunk,
  // lane l -> row ch*4+(l>>4), LDS slot l&15 holds global 16B-slot
  // (l&15)^(row&15)  (XOR swizzle, involution).
  auto STAGE_X = [&](int it, int bsel) {
    unsigned char* xbp = lds + bsel * 32768;
    #pragma unroll
    for (int i = 0; i < 4; ++i) {
      const int ch = wv * 4 + i;                   // 0..31
      const int r = ch * 4 + (lane >> 4);          // row within tile 0..127
      const int c = (lane & 15) ^ (r & 15);        // source 16B slot
      const float* src = x + (tile + r) * KD + it * 64 + c * 4;
      __builtin_amdgcn_global_load_lds(
          (const __attribute__((address_space(1))) void*)src,
          (__attribute__((address_space(3))) void*)(xbp + ch * 1024), 16, 0, 0);
    }
  };
  auto COMPUTE = [&](int it, int xbsel) {
    const unsigned char* xbp = lds + xbsel * 32768;
    const unsigned char* wbp = lds + 98304 + (it & 1) * 18432;
    const int r = wv * 16 + r15;                   // 0..127 ; r&15 == r15
    const unsigned char* xr = xbp + r * 256;
    #pragma unroll
    for (int kh = 0; kh < 2; ++kh) {
      const int c0 = kh * 8 + g * 2;
      f32x4_t lo = *(const f32x4_t*)(xr + ((c0       ^ r15) * 16));
      f32x4_t hi = *(const f32x4_t*)(xr + (((c0 + 1) ^ r15) * 16));
      bf16x8_t af;
      af[0] = (__bf16)lo[0]; af[1] = (__bf16)lo[1];
      af[2] = (__bf16)lo[2]; af[3] = (__bf16)lo[3];
      af[4] = (__bf16)hi[0]; af[5] = (__bf16)hi[1];
      af[6] = (__bf16)hi[2]; af[7] = (__bf16)hi[3];
      #pragma unroll
      for (int nf = 0; nf < 9; ++nf) {
        bf16x8_t bfr = *(const bf16x8_t*)(wbp + ((kh * 9 + nf) * 64 + lane) * 16);
        acc[nf] = __builtin_amdgcn_mfma_f32_16x16x32_bf16(af, bfr, acc[nf], 0, 0, 0);
      }
    }
  };

  // prologue: per-wave queue [W(0):2-3, X(0):4, X(1):4]
  STAGE_W(0);
  STAGE_X(0, 0);
  STAGE_X(1, 1);

  int xb = 0;                                      // buffer of tile `it` (it % 3)
  for (int it = 0; it < 31; ++it) {
    // drains W(it), X(it); leaves X(it+1) (4 loads/wave = 32 KB/CU) in flight
    asm volatile("s_waitcnt vmcnt(4)" ::: "memory");
    __builtin_amdgcn_s_barrier();
    __builtin_amdgcn_sched_barrier(0);
    STAGE_W(it + 1);                               // buf (it+1)&1, freed by barrier
    if (it < 30) {
      int b2 = xb + 2; if (b2 >= 3) b2 -= 3;
      STAGE_X(it + 2, b2);                         // buf (it+2)%3, freed by barrier
    }
    COMPUTE(it, xb);
    ++xb; if (xb == 3) xb = 0;
  }
  // peeled last step: full drain
  asm volatile("s_waitcnt vmcnt(0)" ::: "memory");
  __builtin_amdgcn_s_barrier();
  __builtin_amdgcn_sched_barrier(0);
  COMPUTE(31, xb);

  // epilogue: C col=lane&15, row=g*4+reg; a-frag nf pairs with b-frag nf+4.
  // acc[8][r] (col 128) = qkv+z fold, already at the writer lane (r15==0).
  #pragma unroll
  for (int r = 0; r < 4; ++r) {
    float v = 0.f;
    #pragma unroll
    for (int nf = 0; nf < 4; ++nf) {
      float av = acc[nf][r];
      float bv = acc[nf + 4][r];
      v += av / (1.f + __expf(-bv));          // a * sigmoid(b)
    }
    v += __shfl_xor(v, 1, 64);
    v += __shfl_xor(v, 2, 64);
    v += __shfl_xor(v, 4, 64);
    v += __shfl_xor(v, 8, 64);
    if (r15 == 0) out[tile + wv * 16 + g * 4 + r] = v + acc[8][r];
  }
}

extern "C" void kernel_launch(void* const* d_in, const int* in_sizes, int n_in,
                              void* d_out, int out_size, void* d_ws, size_t ws_size,
                              hipStream_t stream) {
  const float* x    = (const float*)d_in[0];
  const float* wqkv = (const float*)d_in[1];
  const float* wz   = (const float*)d_in[2];
  const float* wb   = (const float*)d_in[3];   // dict order: w_b before w_a
  const float* wa   = (const float*)d_in[4];
  float* out = (float*)d_out;

  unsigned short* wbf3 = (unsigned short*)d_ws;  // 64*9*64*8 shorts = 576 KB

  k_prep<<<400, 256, 0, stream>>>(wqkv, wz, wb, wa, wbf3);
  k_main<<<out_size / 128, 512, 0, stream>>>(x, wbf3, out);
}